// Round 1
// baseline (424.480 us; speedup 1.0000x reference)
//
#include <hip/hip_runtime.h>
#include <stdint.h>

// BondFastAttention on MI355X (gfx950)
// B=64 graphs x L=1024 bonds, HID=512, HEADS=8, D=64. Contiguous equal scopes
// -> pad_sequence == reshape, so batch_scopes is ignored.
//
// Pipeline:
//   K0 cvt_x:    X f32 -> bf16                     (Xb)
//   K0b cvt_w:   Wq|Wk|Wv -> Wqkv bf16 (1536x512), Wo -> bf16
//   K1 gemm<0>:  QKV = Xb @ Wqkv^T  (bf16 out, row = [q|k|v] per token)
//   K2 reduce:   per (b,h): alpha=softmax_D(q*wa*s), gq=sum_l alpha*q;
//                p=gq*k, beta=softmax_D(p*wb*s), gk=sum_l beta*p
//   K3 att:      att = relu( V_h @ (Wr*gk_h)^T + Q_h )  bf16  (MFMA, M in LDS)
//   K4 gemm<1>:  out = att @ Wo^T + bo  (f32 into d_out)
//   K5 ln:       LayerNorm rows of d_out in place
//
// ws layout (bytes):  Xb 0..67108864 | Wqkv ..68681728 | Wob ..69206016 |
//                     QKV ..270532608 | gk ..270663680   (~258 MiB total)
// att aliases Xb (Xb dead after K1).

#define SCALE_F 0.125f   // D^-0.5
#define EPSF 1e-5f

typedef __attribute__((ext_vector_type(8))) short short8;
typedef __attribute__((ext_vector_type(4))) float float4v;
typedef unsigned short ushort_t;

__device__ __forceinline__ ushort_t f2bf(float f) {
  uint32_t u = __builtin_bit_cast(uint32_t, f);
  u += 0x7fffu + ((u >> 16) & 1u);          // round-to-nearest-even
  return (ushort_t)(u >> 16);
}
__device__ __forceinline__ float bf2f(ushort_t s) {
  uint32_t u = ((uint32_t)s) << 16;
  return __builtin_bit_cast(float, u);
}

// async global->LDS, 16B per lane; LDS dest = wave-uniform base + lane*16
__device__ __forceinline__ void gload16(const void* g, void* l) {
  __builtin_amdgcn_global_load_lds(
      (__attribute__((address_space(1))) char*)(char*)const_cast<void*>(g),
      (__attribute__((address_space(3))) char*)(char*)l, 16, 0, 0);
}

// ---------------- K0: X f32 -> bf16 (8 elems/thread) ----------------
__global__ __launch_bounds__(256) void cvt_x(const float* __restrict__ X,
                                             ushort_t* __restrict__ Xb) {
  const int i = blockIdx.x * 256 + threadIdx.x;   // one per 8 elems
  const float4v* src = (const float4v*)X;
  float4v v0 = src[(size_t)i * 2];
  float4v v1 = src[(size_t)i * 2 + 1];
  short8 o;
#pragma unroll
  for (int j = 0; j < 4; ++j) {
    o[j]     = (short)f2bf(v0[j]);
    o[j + 4] = (short)f2bf(v1[j]);
  }
  ((short8*)Xb)[i] = o;
}

// ---------------- K0b: weights -> bf16 ----------------
__global__ __launch_bounds__(256) void cvt_w(const float* __restrict__ Wq,
                                             const float* __restrict__ Wk,
                                             const float* __restrict__ Wv,
                                             const float* __restrict__ Wo,
                                             ushort_t* __restrict__ Wqkv,
                                             ushort_t* __restrict__ Wob) {
  const int i = blockIdx.x * 256 + threadIdx.x;   // 1,048,576 total
  if (i < 262144)        Wqkv[i] = f2bf(Wq[i]);
  else if (i < 524288)   Wqkv[i] = f2bf(Wk[i - 262144]);
  else if (i < 786432)   Wqkv[i] = f2bf(Wv[i - 524288]);
  else                   Wob[i - 786432] = f2bf(Wo[i - 786432]);
}

// ---------------- K1/K4: C = A @ B^T, 128x128 tile, BK=64 (m97 structure) ---
// A: (M x K) bf16 row-major; Bm: (N x K) bf16 row-major (i.e. B^T input).
// MODE 0: C bf16.  MODE 1: C f32 + bias[col].
template <int MODE>
__global__ __launch_bounds__(256) void gemm_bt(const ushort_t* __restrict__ A,
                                               const ushort_t* __restrict__ Bm,
                                               void* __restrict__ Cout,
                                               const float* __restrict__ bias,
                                               int N, int K) {
  __shared__ __align__(16) ushort_t As[128 * 64];
  __shared__ __align__(16) ushort_t Bs[128 * 64];
  const int tn = blockIdx.x, tm = blockIdx.y;   // x = N-tile so A-panel is shared
  const int row0 = tm * 128, col0 = tn * 128;
  const int tid = threadIdx.x, wid = tid >> 6, lane = tid & 63;
  const int wr = wid >> 1, wc = wid & 1;        // 2x2 waves, 64x64 each
  const int lr = lane & 15, lk = lane >> 4;
  float4v acc[4][4] = {};
  const int KB = K * 2;                         // bytes per row
  for (int kt = 0; kt < K; kt += 64) {
    __syncthreads();
#pragma unroll
    for (int i = 0; i < 4; ++i) {
      const int dst = i * 4096 + wid * 1024;    // wave-uniform LDS byte base
      const int off = dst + lane * 16;
      const int r = off >> 7, cb = off & 127;   // row, byte-in-row of [128][64]bf16
      gload16((const char*)A + (size_t)(row0 + r) * KB + kt * 2 + cb, (char*)As + dst);
      gload16((const char*)Bm + (size_t)(col0 + r) * KB + kt * 2 + cb, (char*)Bs + dst);
    }
    asm volatile("s_waitcnt vmcnt(0)" ::: "memory");
    __syncthreads();
#pragma unroll
    for (int ks = 0; ks < 2; ++ks) {
      short8 a[4], b[4];
#pragma unroll
      for (int mi = 0; mi < 4; ++mi)
        a[mi] = *(const short8*)((const char*)As + (wr * 64 + mi * 16 + lr) * 128 + ks * 64 + lk * 16);
#pragma unroll
      for (int ni = 0; ni < 4; ++ni)
        b[ni] = *(const short8*)((const char*)Bs + (wc * 64 + ni * 16 + lr) * 128 + ks * 64 + lk * 16);
#pragma unroll
      for (int mi = 0; mi < 4; ++mi)
#pragma unroll
        for (int ni = 0; ni < 4; ++ni)
          acc[mi][ni] = __builtin_amdgcn_mfma_f32_16x16x32_bf16(a[mi], b[ni], acc[mi][ni], 0, 0, 0);
    }
  }
  // epilogue: D col=lane&15, row=(lane>>4)*4+r  (m89-verified)
#pragma unroll
  for (int mi = 0; mi < 4; ++mi)
#pragma unroll
    for (int ni = 0; ni < 4; ++ni) {
      const int col = col0 + wc * 64 + ni * 16 + lr;
#pragma unroll
      for (int r = 0; r < 4; ++r) {
        const int row = row0 + wr * 64 + mi * 16 + lk * 4 + r;
        const float v = acc[mi][ni][r];
        if (MODE == 0)
          ((ushort_t*)Cout)[(size_t)row * N + col] = f2bf(v);
        else
          ((float*)Cout)[(size_t)row * N + col] = v + bias[col];
      }
    }
}

// ---------------- K2: per-(b,h) alpha/gq then beta/gk ----------------
// QKV row layout per token: [q(512) | k(512) | v(512)], head slice h*64.
// Wave maps lane = 8*row_sub + d_chunk: 8 rows x (8 bf16) per 16B load.
// Row softmax over D=64 -> intra-lane over 8 + shfl_xor {1,2,4}.
__global__ __launch_bounds__(256) void reduce_kernel(const ushort_t* __restrict__ QKV,
                                                     const float* __restrict__ w_alpha,
                                                     const float* __restrict__ w_beta,
                                                     float* __restrict__ gk_out) {
  const int bh = blockIdx.x, b = bh >> 3, h = bh & 7;
  const int tid = threadIdx.x, wid = tid >> 6, lane = tid & 63;
  const int rsub = lane >> 3, dch = lane & 7;
  __shared__ float red[4][64];
  __shared__ float gq_s[64];
  float wa[8], wb[8];
#pragma unroll
  for (int j = 0; j < 8; ++j) {
    wa[j] = w_alpha[dch * 8 + j] * SCALE_F;
    wb[j] = w_beta[dch * 8 + j] * SCALE_F;
  }
  const size_t base = (size_t)b * 1024;
  float acc[8] = {0, 0, 0, 0, 0, 0, 0, 0};
  for (int it = 0; it < 32; ++it) {
    const size_t t = base + it * 32 + wid * 8 + rsub;
    short8 raw = *(const short8*)(QKV + t * 1536 + h * 64 + dch * 8);
    float q[8], s[8];
#pragma unroll
    for (int j = 0; j < 8; ++j) { q[j] = bf2f((ushort_t)raw[j]); s[j] = q[j] * wa[j]; }
    float m = s[0];
#pragma unroll
    for (int j = 1; j < 8; ++j) m = fmaxf(m, s[j]);
    m = fmaxf(m, __shfl_xor(m, 1)); m = fmaxf(m, __shfl_xor(m, 2)); m = fmaxf(m, __shfl_xor(m, 4));
    float e[8], sum = 0.f;
#pragma unroll
    for (int j = 0; j < 8; ++j) { e[j] = __expf(s[j] - m); sum += e[j]; }
    sum += __shfl_xor(sum, 1); sum += __shfl_xor(sum, 2); sum += __shfl_xor(sum, 4);
    const float inv = 1.0f / sum;
#pragma unroll
    for (int j = 0; j < 8; ++j) acc[j] += e[j] * inv * q[j];
  }
#pragma unroll
  for (int msk = 8; msk < 64; msk <<= 1)
#pragma unroll
    for (int j = 0; j < 8; ++j) acc[j] += __shfl_xor(acc[j], msk);
  if (lane < 8) {
#pragma unroll
    for (int j = 0; j < 8; ++j) red[wid][lane * 8 + j] = acc[j];
  }
  __syncthreads();
  if (tid < 64) gq_s[tid] = red[0][tid] + red[1][tid] + red[2][tid] + red[3][tid];
  __syncthreads();
  float gq[8];
#pragma unroll
  for (int j = 0; j < 8; ++j) gq[j] = gq_s[dch * 8 + j];
  float gkacc[8] = {0, 0, 0, 0, 0, 0, 0, 0};
  for (int it = 0; it < 32; ++it) {
    const size_t t = base + it * 32 + wid * 8 + rsub;
    short8 raw = *(const short8*)(QKV + t * 1536 + 512 + h * 64 + dch * 8);
    float p[8], s[8];
#pragma unroll
    for (int j = 0; j < 8; ++j) { p[j] = gq[j] * bf2f((ushort_t)raw[j]); s[j] = p[j] * wb[j]; }
    float m = s[0];
#pragma unroll
    for (int j = 1; j < 8; ++j) m = fmaxf(m, s[j]);
    m = fmaxf(m, __shfl_xor(m, 1)); m = fmaxf(m, __shfl_xor(m, 2)); m = fmaxf(m, __shfl_xor(m, 4));
    float e[8], sum = 0.f;
#pragma unroll
    for (int j = 0; j < 8; ++j) { e[j] = __expf(s[j] - m); sum += e[j]; }
    sum += __shfl_xor(sum, 1); sum += __shfl_xor(sum, 2); sum += __shfl_xor(sum, 4);
    const float inv = 1.0f / sum;
#pragma unroll
    for (int j = 0; j < 8; ++j) gkacc[j] += e[j] * inv * p[j];
  }
#pragma unroll
  for (int msk = 8; msk < 64; msk <<= 1)
#pragma unroll
    for (int j = 0; j < 8; ++j) gkacc[j] += __shfl_xor(gkacc[j], msk);
  if (lane < 8) {
#pragma unroll
    for (int j = 0; j < 8; ++j) red[wid][lane * 8 + j] = gkacc[j];
  }
  __syncthreads();
  if (tid < 64) gk_out[bh * 64 + tid] = red[0][tid] + red[1][tid] + red[2][tid] + red[3][tid];
}

// ---------------- K3: att = relu(V_h @ M^T + Q_h), M[e][d] = Wr[e][d]*gk[d] --
// One block per (b,h). M in LDS bf16 padded to 72/row (2-way banks = free).
// A-frags (V) read direct from global (coalesces to full 64B lines per 16-row
// group); Q added scalar in epilogue.
__global__ __launch_bounds__(256) void att_kernel(const ushort_t* __restrict__ QKV,
                                                  const float* __restrict__ Wr,
                                                  const float* __restrict__ gk,
                                                  ushort_t* __restrict__ att) {
  const int bh = blockIdx.x, b = bh >> 3, h = bh & 7;
  __shared__ __align__(16) ushort_t Ml[64 * 72];
  const float* gkh = gk + bh * 64;
  for (int i = threadIdx.x; i < 4096; i += 256) {
    const int e = i >> 6, d = i & 63;
    Ml[e * 72 + d] = f2bf(Wr[i] * gkh[d]);
  }
  __syncthreads();
  const int tid = threadIdx.x, wid = tid >> 6, lane = tid & 63;
  const int lr = lane & 15, lk = lane >> 4;
  short8 bfr[4][2];
#pragma unroll
  for (int ni = 0; ni < 4; ++ni)
#pragma unroll
    for (int ks = 0; ks < 2; ++ks)
      bfr[ni][ks] = *(const short8*)&Ml[(ni * 16 + lr) * 72 + ks * 32 + lk * 8];
  const size_t tw = (size_t)b * 1024 + wid * 256;  // wave owns 256 tokens
  for (int c = 0; c < 4; ++c) {
    float4v acc[4][4] = {};
#pragma unroll
    for (int ks = 0; ks < 2; ++ks) {
      short8 a[4];
#pragma unroll
      for (int mi = 0; mi < 4; ++mi) {
        const size_t t = tw + c * 64 + mi * 16 + lr;
        a[mi] = *(const short8*)(QKV + t * 1536 + 1024 + h * 64 + ks * 32 + lk * 8);
      }
#pragma unroll
      for (int mi = 0; mi < 4; ++mi)
#pragma unroll
        for (int ni = 0; ni < 4; ++ni)
          acc[mi][ni] = __builtin_amdgcn_mfma_f32_16x16x32_bf16(a[mi], bfr[ni][ks], acc[mi][ni], 0, 0, 0);
    }
#pragma unroll
    for (int mi = 0; mi < 4; ++mi)
#pragma unroll
      for (int ni = 0; ni < 4; ++ni)
#pragma unroll
        for (int r = 0; r < 4; ++r) {
          const size_t t = tw + c * 64 + mi * 16 + lk * 4 + r;
          const int e = ni * 16 + lr;
          float v = acc[mi][ni][r] + bf2f(QKV[t * 1536 + h * 64 + e]);
          v = fmaxf(v, 0.0f);
          att[t * 512 + h * 64 + e] = f2bf(v);
        }
  }
}

// ---------------- K5: LayerNorm in place, one wave per row ----------------
__global__ __launch_bounds__(256) void ln_kernel(float* __restrict__ out,
                                                 const float* __restrict__ g,
                                                 const float* __restrict__ bta) {
  const int row = blockIdx.x * 4 + (threadIdx.x >> 6);
  const int lane = threadIdx.x & 63;
  float* p = out + (size_t)row * 512 + lane * 8;
  float4v x0 = ((float4v*)p)[0], x1 = ((float4v*)p)[1];
  float s = 0.f, ss = 0.f;
#pragma unroll
  for (int j = 0; j < 4; ++j) {
    s += x0[j] + x1[j];
    ss += x0[j] * x0[j] + x1[j] * x1[j];
  }
#pragma unroll
  for (int m = 1; m < 64; m <<= 1) { s += __shfl_xor(s, m); ss += __shfl_xor(ss, m); }
  const float mu = s * (1.f / 512.f);
  const float var = ss * (1.f / 512.f) - mu * mu;
  const float rs = rsqrtf(var + EPSF);
  const float4v* gv = (const float4v*)(g + lane * 8);
  const float4v* bv = (const float4v*)(bta + lane * 8);
  const float4v g0 = gv[0], g1 = gv[1], b0 = bv[0], b1 = bv[1];
#pragma unroll
  for (int j = 0; j < 4; ++j) {
    x0[j] = (x0[j] - mu) * rs * g0[j] + b0[j];
    x1[j] = (x1[j] - mu) * rs * g1[j] + b1[j];
  }
  ((float4v*)p)[0] = x0;
  ((float4v*)p)[1] = x1;
}

extern "C" void kernel_launch(void* const* d_in, const int* in_sizes, int n_in,
                              void* d_out, int out_size, void* d_ws, size_t ws_size,
                              hipStream_t stream) {
  const float* X       = (const float*)d_in[0];
  // d_in[1] = batch_scopes (int64) — contiguous equal scopes, unused
  const float* Wq      = (const float*)d_in[2];
  const float* Wk      = (const float*)d_in[3];
  const float* Wv      = (const float*)d_in[4];
  const float* Wr      = (const float*)d_in[5];
  const float* w_alpha = (const float*)d_in[6];
  const float* w_beta  = (const float*)d_in[7];
  const float* Wo      = (const float*)d_in[8];
  const float* bo      = (const float*)d_in[9];
  const float* ln_g    = (const float*)d_in[10];
  const float* ln_b    = (const float*)d_in[11];

  char* ws = (char*)d_ws;
  ushort_t* Xb   = (ushort_t*)(ws);                 // 67,108,864 B
  ushort_t* Wqkv = (ushort_t*)(ws + 67108864);      //  1,572,864 B
  ushort_t* Wob  = (ushort_t*)(ws + 68681728);      //    524,288 B
  ushort_t* QKV  = (ushort_t*)(ws + 69206016);      // 201,326,592 B
  float*    gk   = (float*)(ws + 270532608);        //    131,072 B
  ushort_t* att  = Xb;                              // alias: Xb dead after K1
  float* out = (float*)d_out;

  hipLaunchKernelGGL(cvt_x, dim3(16384), dim3(256), 0, stream, X, Xb);
  hipLaunchKernelGGL(cvt_w, dim3(4096), dim3(256), 0, stream, Wq, Wk, Wv, Wo, Wqkv, Wob);
  hipLaunchKernelGGL((gemm_bt<0>), dim3(12, 512), dim3(256), 0, stream,
                     Xb, Wqkv, (void*)QKV, (const float*)nullptr, 1536, 512);
  hipLaunchKernelGGL(reduce_kernel, dim3(512), dim3(256), 0, stream, QKV, w_alpha, w_beta, gk);
  hipLaunchKernelGGL(att_kernel, dim3(512), dim3(256), 0, stream, QKV, Wr, gk, att);
  hipLaunchKernelGGL((gemm_bt<1>), dim3(4, 512), dim3(256), 0, stream,
                     att, Wob, (void*)out, bo, 512, 512);
  hipLaunchKernelGGL(ln_kernel, dim3(16384), dim3(256), 0, stream, out, ln_g, ln_b);
}

// Round 2
// 403.202 us; speedup vs baseline: 1.0528x; 1.0528x over previous
//
#include <hip/hip_runtime.h>
#include <stdint.h>

// BondFastAttention on MI355X (gfx950)
// B=64 graphs x L=1024 bonds, HID=512, HEADS=8, D=64. Contiguous equal scopes
// -> pad_sequence == reshape, so batch_scopes is ignored.
//
// Pipeline (round 2):
//   K0  cvt_x:      X f32 -> bf16                     (Xb)
//   K0b cvt_w:      Wq|Wk|Wv -> Wqkv bf16 (1536x512), Wo -> bf16
//   K1  gemm_bt<0>: QKV = Xb @ Wqkv^T  (bf16, row = [q|k|v] per token)
//   K2  reduce_att: per (b,h): alpha/gq, beta/gk (LDS), M=Wr*gk,
//                   att = relu(V @ M^T + Q)  (fused, gk never leaves LDS)
//   K3  gemm_ln:    out = LN(att @ Wo^T + bo)*g + b   (f32 direct to d_out,
//                   LN fused in epilogue: BN=512 = full row per block)
//
// ws: Xb 0..67108864 | Wqkv ..68681728 | Wob ..69206016 | QKV ..270532608
// att aliases Xb (Xb dead after K1).

#define SCALE_F 0.125f   // D^-0.5
#define EPSF 1e-5f

typedef __attribute__((ext_vector_type(8))) short short8;
typedef __attribute__((ext_vector_type(4))) float float4v;
typedef unsigned short ushort_t;

__device__ __forceinline__ ushort_t f2bf(float f) {
  uint32_t u = __builtin_bit_cast(uint32_t, f);
  u += 0x7fffu + ((u >> 16) & 1u);          // round-to-nearest-even
  return (ushort_t)(u >> 16);
}
__device__ __forceinline__ float bf2f(ushort_t s) {
  uint32_t u = ((uint32_t)s) << 16;
  return __builtin_bit_cast(float, u);
}

// async global->LDS, 16B per lane; LDS dest = wave-uniform base + lane*16
__device__ __forceinline__ void gload16(const void* g, void* l) {
  __builtin_amdgcn_global_load_lds(
      (__attribute__((address_space(1))) char*)(char*)const_cast<void*>(g),
      (__attribute__((address_space(3))) char*)(char*)l, 16, 0, 0);
}

// ---------------- K0: X f32 -> bf16 (8 elems/thread) ----------------
__global__ __launch_bounds__(256) void cvt_x(const float* __restrict__ X,
                                             ushort_t* __restrict__ Xb) {
  const int i = blockIdx.x * 256 + threadIdx.x;
  const float4v* src = (const float4v*)X;
  float4v v0 = src[(size_t)i * 2];
  float4v v1 = src[(size_t)i * 2 + 1];
  short8 o;
#pragma unroll
  for (int j = 0; j < 4; ++j) {
    o[j]     = (short)f2bf(v0[j]);
    o[j + 4] = (short)f2bf(v1[j]);
  }
  ((short8*)Xb)[i] = o;
}

// ---------------- K0b: weights -> bf16 ----------------
__global__ __launch_bounds__(256) void cvt_w(const float* __restrict__ Wq,
                                             const float* __restrict__ Wk,
                                             const float* __restrict__ Wv,
                                             const float* __restrict__ Wo,
                                             ushort_t* __restrict__ Wqkv,
                                             ushort_t* __restrict__ Wob) {
  const int i = blockIdx.x * 256 + threadIdx.x;   // 1,048,576 total
  if (i < 262144)        Wqkv[i] = f2bf(Wq[i]);
  else if (i < 524288)   Wqkv[i] = f2bf(Wk[i - 262144]);
  else if (i < 786432)   Wqkv[i] = f2bf(Wv[i - 524288]);
  else                   Wob[i - 786432] = f2bf(Wo[i - 786432]);
}

// ---------------- K1: C = A @ B^T, 128x128 tile, BK=64 (m97 structure) ------
template <int MODE>
__global__ __launch_bounds__(256) void gemm_bt(const ushort_t* __restrict__ A,
                                               const ushort_t* __restrict__ Bm,
                                               void* __restrict__ Cout,
                                               const float* __restrict__ bias,
                                               int N, int K) {
  __shared__ __align__(16) ushort_t As[128 * 64];
  __shared__ __align__(16) ushort_t Bs[128 * 64];
  const int tn = blockIdx.x, tm = blockIdx.y;
  const int row0 = tm * 128, col0 = tn * 128;
  const int tid = threadIdx.x, wid = tid >> 6, lane = tid & 63;
  const int wr = wid >> 1, wc = wid & 1;
  const int lr = lane & 15, lk = lane >> 4;
  float4v acc[4][4] = {};
  const int KB = K * 2;
  for (int kt = 0; kt < K; kt += 64) {
    __syncthreads();
#pragma unroll
    for (int i = 0; i < 4; ++i) {
      const int dst = i * 4096 + wid * 1024;
      const int off = dst + lane * 16;
      const int r = off >> 7, cb = off & 127;
      gload16((const char*)A + (size_t)(row0 + r) * KB + kt * 2 + cb, (char*)As + dst);
      gload16((const char*)Bm + (size_t)(col0 + r) * KB + kt * 2 + cb, (char*)Bs + dst);
    }
    asm volatile("s_waitcnt vmcnt(0)" ::: "memory");
    __syncthreads();
#pragma unroll
    for (int ks = 0; ks < 2; ++ks) {
      short8 a[4], b[4];
#pragma unroll
      for (int mi = 0; mi < 4; ++mi)
        a[mi] = *(const short8*)((const char*)As + (wr * 64 + mi * 16 + lr) * 128 + ks * 64 + lk * 16);
#pragma unroll
      for (int ni = 0; ni < 4; ++ni)
        b[ni] = *(const short8*)((const char*)Bs + (wc * 64 + ni * 16 + lr) * 128 + ks * 64 + lk * 16);
#pragma unroll
      for (int mi = 0; mi < 4; ++mi)
#pragma unroll
        for (int ni = 0; ni < 4; ++ni)
          acc[mi][ni] = __builtin_amdgcn_mfma_f32_16x16x32_bf16(a[mi], b[ni], acc[mi][ni], 0, 0, 0);
    }
  }
#pragma unroll
  for (int mi = 0; mi < 4; ++mi)
#pragma unroll
    for (int ni = 0; ni < 4; ++ni) {
      const int col = col0 + wc * 64 + ni * 16 + lr;
#pragma unroll
      for (int r = 0; r < 4; ++r) {
        const int row = row0 + wr * 64 + mi * 16 + lk * 4 + r;
        const float v = acc[mi][ni][r];
        if (MODE == 0)
          ((ushort_t*)Cout)[(size_t)row * N + col] = f2bf(v);
        else
          ((float*)Cout)[(size_t)row * N + col] = v + bias[col];
      }
    }
}

// ---------------- K2: fused reduce (alpha/gq, beta/gk) + att ----------------
// One block per (b,h), 512 threads (8 waves). gk stays in LDS.
// QKV row layout per token: [q(512) | k(512) | v(512)], head slice h*64.
__global__ __launch_bounds__(512) void reduce_att(const ushort_t* __restrict__ QKV,
                                                  const float* __restrict__ Wr,
                                                  const float* __restrict__ w_alpha,
                                                  const float* __restrict__ w_beta,
                                                  ushort_t* __restrict__ att) {
  const int bh = blockIdx.x, b = bh >> 3, h = bh & 7;
  const int tid = threadIdx.x, wid = tid >> 6, lane = tid & 63;
  const int rsub = lane >> 3, dch = lane & 7;
  __shared__ float red[8][64];
  __shared__ float gq_s[64];
  __shared__ float gk_s[64];
  __shared__ __align__(16) ushort_t Ml[64 * 72];
  float wa[8], wb[8];
#pragma unroll
  for (int j = 0; j < 8; ++j) {
    wa[j] = w_alpha[dch * 8 + j] * SCALE_F;
    wb[j] = w_beta[dch * 8 + j] * SCALE_F;
  }
  const size_t base = (size_t)b * 1024;
  // ---- pass 1: alpha = softmax_D(q*wa), gq = sum_l alpha*q ----
  float acc[8] = {0, 0, 0, 0, 0, 0, 0, 0};
  for (int it = 0; it < 16; ++it) {
    const size_t t = base + it * 64 + wid * 8 + rsub;
    short8 raw = *(const short8*)(QKV + t * 1536 + h * 64 + dch * 8);
    float q[8], s[8];
#pragma unroll
    for (int j = 0; j < 8; ++j) { q[j] = bf2f((ushort_t)raw[j]); s[j] = q[j] * wa[j]; }
    float m = s[0];
#pragma unroll
    for (int j = 1; j < 8; ++j) m = fmaxf(m, s[j]);
    m = fmaxf(m, __shfl_xor(m, 1)); m = fmaxf(m, __shfl_xor(m, 2)); m = fmaxf(m, __shfl_xor(m, 4));
    float e[8], sum = 0.f;
#pragma unroll
    for (int j = 0; j < 8; ++j) { e[j] = __expf(s[j] - m); sum += e[j]; }
    sum += __shfl_xor(sum, 1); sum += __shfl_xor(sum, 2); sum += __shfl_xor(sum, 4);
    const float inv = 1.0f / sum;
#pragma unroll
    for (int j = 0; j < 8; ++j) acc[j] += e[j] * inv * q[j];
  }
#pragma unroll
  for (int msk = 8; msk < 64; msk <<= 1)
#pragma unroll
    for (int j = 0; j < 8; ++j) acc[j] += __shfl_xor(acc[j], msk);
  if (lane < 8) {
#pragma unroll
    for (int j = 0; j < 8; ++j) red[wid][lane * 8 + j] = acc[j];
  }
  __syncthreads();
  if (tid < 64) {
    float s = 0.f;
#pragma unroll
    for (int w = 0; w < 8; ++w) s += red[w][tid];
    gq_s[tid] = s;
  }
  __syncthreads();
  float gq[8];
#pragma unroll
  for (int j = 0; j < 8; ++j) gq[j] = gq_s[dch * 8 + j];
  // ---- pass 2: p = gq*k, beta = softmax_D(p*wb), gk = sum_l beta*p ----
  float gkacc[8] = {0, 0, 0, 0, 0, 0, 0, 0};
  for (int it = 0; it < 16; ++it) {
    const size_t t = base + it * 64 + wid * 8 + rsub;
    short8 raw = *(const short8*)(QKV + t * 1536 + 512 + h * 64 + dch * 8);
    float p[8], s[8];
#pragma unroll
    for (int j = 0; j < 8; ++j) { p[j] = gq[j] * bf2f((ushort_t)raw[j]); s[j] = p[j] * wb[j]; }
    float m = s[0];
#pragma unroll
    for (int j = 1; j < 8; ++j) m = fmaxf(m, s[j]);
    m = fmaxf(m, __shfl_xor(m, 1)); m = fmaxf(m, __shfl_xor(m, 2)); m = fmaxf(m, __shfl_xor(m, 4));
    float e[8], sum = 0.f;
#pragma unroll
    for (int j = 0; j < 8; ++j) { e[j] = __expf(s[j] - m); sum += e[j]; }
    sum += __shfl_xor(sum, 1); sum += __shfl_xor(sum, 2); sum += __shfl_xor(sum, 4);
    const float inv = 1.0f / sum;
#pragma unroll
    for (int j = 0; j < 8; ++j) gkacc[j] += e[j] * inv * p[j];
  }
#pragma unroll
  for (int msk = 8; msk < 64; msk <<= 1)
#pragma unroll
    for (int j = 0; j < 8; ++j) gkacc[j] += __shfl_xor(gkacc[j], msk);
  if (lane < 8) {
#pragma unroll
    for (int j = 0; j < 8; ++j) red[wid][lane * 8 + j] = gkacc[j];
  }
  __syncthreads();
  if (tid < 64) {
    float s = 0.f;
#pragma unroll
    for (int w = 0; w < 8; ++w) s += red[w][tid];
    gk_s[tid] = s;
  }
  __syncthreads();
  // ---- M = Wr * gk (row e scaled per-col d), bf16 in LDS (pad 72) ----
  for (int i = tid; i < 4096; i += 512) {
    const int e = i >> 6, d = i & 63;
    Ml[e * 72 + d] = f2bf(Wr[i] * gk_s[d]);
  }
  __syncthreads();
  // ---- att = relu(V @ M^T + Q): 8 waves x 128 tokens each ----
  const int lr = lane & 15, lk = lane >> 4;
  short8 bfr[4][2];
#pragma unroll
  for (int ni = 0; ni < 4; ++ni)
#pragma unroll
    for (int ks = 0; ks < 2; ++ks)
      bfr[ni][ks] = *(const short8*)&Ml[(ni * 16 + lr) * 72 + ks * 32 + lk * 8];
  const size_t tw = base + wid * 128;
  for (int c = 0; c < 2; ++c) {
    float4v oacc[4][4] = {};
#pragma unroll
    for (int ks = 0; ks < 2; ++ks) {
      short8 a[4];
#pragma unroll
      for (int mi = 0; mi < 4; ++mi) {
        const size_t t = tw + c * 64 + mi * 16 + lr;
        a[mi] = *(const short8*)(QKV + t * 1536 + 1024 + h * 64 + ks * 32 + lk * 8);
      }
#pragma unroll
      for (int mi = 0; mi < 4; ++mi)
#pragma unroll
        for (int ni = 0; ni < 4; ++ni)
          oacc[mi][ni] = __builtin_amdgcn_mfma_f32_16x16x32_bf16(a[mi], bfr[ni][ks], oacc[mi][ni], 0, 0, 0);
    }
#pragma unroll
    for (int mi = 0; mi < 4; ++mi)
#pragma unroll
      for (int ni = 0; ni < 4; ++ni)
#pragma unroll
        for (int r = 0; r < 4; ++r) {
          const size_t t = tw + c * 64 + mi * 16 + lk * 4 + r;
          const int e = ni * 16 + lr;
          float v = oacc[mi][ni][r] + bf2f(QKV[t * 1536 + h * 64 + e]);
          v = fmaxf(v, 0.0f);
          att[t * 512 + h * 64 + e] = f2bf(v);
        }
  }
}

// ---------------- K3: out = LN(att @ Wo^T + bo)*g + b  (fused epilogue) -----
// Grid 512 (M-tiles of 128 rows); 512 threads = 8 waves (2 wr x 4 wc),
// wave tile 64x128, BN=512 (full LN row in-block), BK=32 double-buffered.
__global__ __launch_bounds__(512, 2) void gemm_ln(const ushort_t* __restrict__ A,
                                                  const ushort_t* __restrict__ Bm,
                                                  float* __restrict__ out,
                                                  const float* __restrict__ bo,
                                                  const float* __restrict__ lng,
                                                  const float* __restrict__ lnb) {
  __shared__ __align__(16) ushort_t As[2][128 * 32];   // 2 x 8 KB
  __shared__ __align__(16) ushort_t Bs[2][512 * 32];   // 2 x 32 KB
  __shared__ float red_s[4][128][2];                   // per-wc row partials
  __shared__ float tot_s[128][2];
  const int tid = threadIdx.x, wid = tid >> 6, lane = tid & 63;
  const int wr = wid >> 2, wc = wid & 3;
  const int lr = lane & 15, lk = lane >> 4;
  const int row0 = blockIdx.x * 128;
  float4v acc[4][8] = {};

  const int la = lane * 16;
  const int ar = wid * 16 + (lane >> 2);     // A: wave wid stages rows wid*16..+15
  const int acb = (lane & 3) * 16;           // byte within 64B row

  auto stage = [&](int buf, int s) {
    const int k0b = s * 64;                  // byte offset into 1024B row
    gload16((const char*)A + (size_t)(row0 + ar) * 1024 + k0b + acb,
            (char*)&As[buf][0] + wid * 1024);
#pragma unroll
    for (int i = 0; i < 4; ++i) {
      const int dst = (wid * 4 + i) * 1024;  // B: 32 chunks of 16 rows
      const int br = (dst + la) >> 6;
      const int bcb = la & 63;
      gload16((const char*)Bm + (size_t)br * 1024 + k0b + bcb,
              (char*)&Bs[buf][0] + dst);
    }
  };

  stage(0, 0);
  __syncthreads();                           // implicit vmcnt(0) drain
  for (int s = 0; s < 16; ++s) {
    const int buf = s & 1;
    if (s < 15) stage(buf ^ 1, s + 1);       // prefetch overlaps compute
    short8 af[4], bf[8];
#pragma unroll
    for (int mi = 0; mi < 4; ++mi)
      af[mi] = *(const short8*)((const char*)&As[buf][0] + (wr * 64 + mi * 16 + lr) * 64 + lk * 16);
#pragma unroll
    for (int ni = 0; ni < 8; ++ni)
      bf[ni] = *(const short8*)((const char*)&Bs[buf][0] + (wc * 128 + ni * 16 + lr) * 64 + lk * 16);
#pragma unroll
    for (int mi = 0; mi < 4; ++mi)
#pragma unroll
      for (int ni = 0; ni < 8; ++ni)
        acc[mi][ni] = __builtin_amdgcn_mfma_f32_16x16x32_bf16(af[mi], bf[ni], acc[mi][ni], 0, 0, 0);
    __syncthreads();                         // drains vmcnt; protects dbuf swap
  }

  // ---- epilogue: bias + LayerNorm over the in-register full row ----
  float bov[8], gv[8], bv[8];
#pragma unroll
  for (int ni = 0; ni < 8; ++ni) {
    const int c = wc * 128 + ni * 16 + lr;
    bov[ni] = bo[c]; gv[ni] = lng[c]; bv[ni] = lnb[c];
  }
#pragma unroll
  for (int mi = 0; mi < 4; ++mi)
#pragma unroll
    for (int ni = 0; ni < 8; ++ni)
#pragma unroll
      for (int r = 0; r < 4; ++r)
        acc[mi][ni][r] += bov[ni];
#pragma unroll
  for (int mi = 0; mi < 4; ++mi)
#pragma unroll
    for (int r = 0; r < 4; ++r) {
      float s = 0.f, q = 0.f;
#pragma unroll
      for (int ni = 0; ni < 8; ++ni) { const float v = acc[mi][ni][r]; s += v; q += v * v; }
      s += __shfl_xor(s, 1); q += __shfl_xor(q, 1);
      s += __shfl_xor(s, 2); q += __shfl_xor(q, 2);
      s += __shfl_xor(s, 4); q += __shfl_xor(q, 4);
      s += __shfl_xor(s, 8); q += __shfl_xor(q, 8);
      if (lr == 0) {
        const int rb = wr * 64 + mi * 16 + lk * 4 + r;
        red_s[wc][rb][0] = s;
        red_s[wc][rb][1] = q;
      }
    }
  __syncthreads();
  if (tid < 128) {
    tot_s[tid][0] = red_s[0][tid][0] + red_s[1][tid][0] + red_s[2][tid][0] + red_s[3][tid][0];
    tot_s[tid][1] = red_s[0][tid][1] + red_s[1][tid][1] + red_s[2][tid][1] + red_s[3][tid][1];
  }
  __syncthreads();
#pragma unroll
  for (int mi = 0; mi < 4; ++mi)
#pragma unroll
    for (int r = 0; r < 4; ++r) {
      const int rb = wr * 64 + mi * 16 + lk * 4 + r;
      const float mu = tot_s[rb][0] * (1.f / 512.f);
      const float var = tot_s[rb][1] * (1.f / 512.f) - mu * mu;
      const float rs = rsqrtf(var + EPSF);
      float* op = out + (size_t)(row0 + rb) * 512 + wc * 128 + lr;
#pragma unroll
      for (int ni = 0; ni < 8; ++ni)
        op[ni * 16] = (acc[mi][ni][r] - mu) * rs * gv[ni] + bv[ni];
    }
}

extern "C" void kernel_launch(void* const* d_in, const int* in_sizes, int n_in,
                              void* d_out, int out_size, void* d_ws, size_t ws_size,
                              hipStream_t stream) {
  const float* X       = (const float*)d_in[0];
  // d_in[1] = batch_scopes (int64) — contiguous equal scopes, unused
  const float* Wq      = (const float*)d_in[2];
  const float* Wk      = (const float*)d_in[3];
  const float* Wv      = (const float*)d_in[4];
  const float* Wr      = (const float*)d_in[5];
  const float* w_alpha = (const float*)d_in[6];
  const float* w_beta  = (const float*)d_in[7];
  const float* Wo      = (const float*)d_in[8];
  const float* bo      = (const float*)d_in[9];
  const float* ln_g    = (const float*)d_in[10];
  const float* ln_b    = (const float*)d_in[11];

  char* ws = (char*)d_ws;
  ushort_t* Xb   = (ushort_t*)(ws);                 // 67,108,864 B
  ushort_t* Wqkv = (ushort_t*)(ws + 67108864);      //  1,572,864 B
  ushort_t* Wob  = (ushort_t*)(ws + 68681728);      //    524,288 B
  ushort_t* QKV  = (ushort_t*)(ws + 69206016);      // 201,326,592 B
  ushort_t* att  = Xb;                              // alias: Xb dead after K1
  float* out = (float*)d_out;

  hipLaunchKernelGGL(cvt_x, dim3(16384), dim3(256), 0, stream, X, Xb);
  hipLaunchKernelGGL(cvt_w, dim3(4096), dim3(256), 0, stream, Wq, Wk, Wv, Wo, Wqkv, Wob);
  hipLaunchKernelGGL((gemm_bt<0>), dim3(12, 512), dim3(256), 0, stream,
                     Xb, Wqkv, (void*)QKV, (const float*)nullptr, 1536, 512);
  hipLaunchKernelGGL(reduce_att, dim3(512), dim3(512), 0, stream,
                     QKV, Wr, w_alpha, w_beta, att);
  hipLaunchKernelGGL(gemm_ln, dim3(512), dim3(512), 0, stream,
                     att, Wob, out, bo, ln_g, ln_b);
}

// Round 3
// 371.118 us; speedup vs baseline: 1.1438x; 1.0865x over previous
//
#include <hip/hip_runtime.h>
#include <stdint.h>

// BondFastAttention on MI355X (gfx950)
// B=64 graphs x L=1024 bonds, HID=512, HEADS=8, D=64. Contiguous equal scopes
// -> pad_sequence == reshape, so batch_scopes is ignored.
//
// Pipeline (round 3):
//   K0  cvt_x:   X f32 -> bf16 (Xb)
//   K0b cvt_w:   Wq|Wk|Wv -> Wqkv bf16 (1536x512), Wo -> bf16
//   K1  gemm8p:  QKV = Xb @ Wqkv^T  -- 256^2 tile, BK=64, 8 waves, 4-phase
//                counted-vmcnt schedule + LDS XOR swizzle + setprio + XCD swz
//   K2  reduce_att: per (b,h) alpha/gq, beta/gk in LDS, att = relu(V@M^T + Q)
//   K3  gemm_ln: out = LN(att @ Wo^T + bo)*g + b  (fused epilogue)
//
// ws: Xb 0..67108864 | Wqkv ..68681728 | Wob ..69206016 | QKV ..270532608
// att aliases Xb (Xb dead after K1).

#define SCALE_F 0.125f   // D^-0.5
#define EPSF 1e-5f

typedef __attribute__((ext_vector_type(8))) short short8;
typedef __attribute__((ext_vector_type(4))) float float4v;
typedef unsigned short ushort_t;

__device__ __forceinline__ ushort_t f2bf(float f) {
  uint32_t u = __builtin_bit_cast(uint32_t, f);
  u += 0x7fffu + ((u >> 16) & 1u);          // round-to-nearest-even
  return (ushort_t)(u >> 16);
}
__device__ __forceinline__ float bf2f(ushort_t s) {
  uint32_t u = ((uint32_t)s) << 16;
  return __builtin_bit_cast(float, u);
}

// async global->LDS, 16B per lane; LDS dest = wave-uniform base + lane*16
__device__ __forceinline__ void gload16(const void* g, void* l) {
  __builtin_amdgcn_global_load_lds(
      (__attribute__((address_space(1))) char*)(char*)const_cast<void*>(g),
      (__attribute__((address_space(3))) char*)(char*)l, 16, 0, 0);
}

#define BARR() asm volatile("s_barrier" ::: "memory")
#define LGKM0() do { asm volatile("s_waitcnt lgkmcnt(0)" ::: "memory"); \
                     __builtin_amdgcn_sched_barrier(0); } while (0)

// ---------------- K0: X f32 -> bf16 (8 elems/thread) ----------------
__global__ __launch_bounds__(256) void cvt_x(const float* __restrict__ X,
                                             ushort_t* __restrict__ Xb) {
  const int i = blockIdx.x * 256 + threadIdx.x;
  const float4v* src = (const float4v*)X;
  float4v v0 = src[(size_t)i * 2];
  float4v v1 = src[(size_t)i * 2 + 1];
  short8 o;
#pragma unroll
  for (int j = 0; j < 4; ++j) {
    o[j]     = (short)f2bf(v0[j]);
    o[j + 4] = (short)f2bf(v1[j]);
  }
  ((short8*)Xb)[i] = o;
}

// ---------------- K0b: weights -> bf16 ----------------
__global__ __launch_bounds__(256) void cvt_w(const float* __restrict__ Wq,
                                             const float* __restrict__ Wk,
                                             const float* __restrict__ Wv,
                                             const float* __restrict__ Wo,
                                             ushort_t* __restrict__ Wqkv,
                                             ushort_t* __restrict__ Wob) {
  const int i = blockIdx.x * 256 + threadIdx.x;   // 1,048,576 total
  if (i < 262144)        Wqkv[i] = f2bf(Wq[i]);
  else if (i < 524288)   Wqkv[i] = f2bf(Wk[i - 262144]);
  else if (i < 786432)   Wqkv[i] = f2bf(Wv[i - 524288]);
  else                   Wob[i - 786432] = f2bf(Wo[i - 786432]);
}

// ---------------- K1: QKV = Xb @ Wqkv^T, 256x256 tile, 8-phase schedule -----
// M=65536, N=1536, K=512 fixed. 512 threads = 8 waves (2 wr x 4 wc), wave tile
// 128x64. LDS: 4-slot ring per operand, slot = one half-tile (128 x 64 bf16 =
// 16 KB), XOR-swizzled: element (r, c) stored at byte (r*128 + (c2 ^
// ((r&7)<<4))). global_load_lds writes linearly -> global source pre-swizzled.
// Ledger (per wave, 2 loads/half): prologue 7 halves, vmcnt(6) => K0 landed.
// Per K-tile t: ph1 stage K(t+1)B1, ph3 K(t+2)A0+A1, ph4 K(t+2)B0; boundary
// vmcnt(6) => K(t+1) fully landed (vmcnt(0) at t=6). Slot overwrite is safe:
// reads of a slot finish at ph1/ph2 lgkmcnt(0); its replacement is issued in
// ph3+ (after the intervening barrier).
__global__ __launch_bounds__(512, 2) void gemm8p(const ushort_t* __restrict__ A,
                                                 const ushort_t* __restrict__ Bm,
                                                 ushort_t* __restrict__ C) {
  __shared__ __align__(16) char ldsA[65536];
  __shared__ __align__(16) char ldsB[65536];
  // XCD-chunked swizzle: nwg = 256*6 = 1536, 1536 % 8 == 0 -> bijective
  const int swz = (blockIdx.x & 7) * 192 + (blockIdx.x >> 3);
  const int tm = swz / 6, tn = swz % 6;
  const int row0 = tm * 256, col0 = tn * 256;
  const int tid = threadIdx.x, wid = tid >> 6, lane = tid & 63;
  const int wr = wid >> 2, wc = wid & 3;
  const int lr = lane & 15, lk = lane >> 4;
  const int xr = (lr & 7) << 4;               // read-side XOR (bytes)

  // stage half-tile (kt, h) of A or B into ring slot (2*kt+h)&3
  auto stageA = [&](int kt, int h) {
    const int slot = (2 * kt + h) & 3;
    const int rowbase = row0 + h * 128;
#pragma unroll
    for (int i = 0; i < 2; ++i) {
      const int o = i * 8192 + wid * 1024 + lane * 16;
      const int r = o >> 7, x = o & 127;
      gload16((const char*)A + (size_t)(rowbase + r) * 1024 + kt * 128 + (x ^ ((r & 7) << 4)),
              ldsA + slot * 16384 + i * 8192 + wid * 1024);
    }
  };
  auto stageB = [&](int kt, int h) {
    const int slot = (2 * kt + h) & 3;
    const int rowbase = col0 + h * 128;
#pragma unroll
    for (int i = 0; i < 2; ++i) {
      const int o = i * 8192 + wid * 1024 + lane * 16;
      const int r = o >> 7, x = o & 127;
      gload16((const char*)Bm + (size_t)(rowbase + r) * 1024 + kt * 128 + (x ^ ((r & 7) << 4)),
              ldsB + slot * 16384 + i * 8192 + wid * 1024);
    }
  };
  auto rdA = [&](int t, int mi, int kk) -> short8 {
    const int slot = (2 * t + wr) & 3;
    return *(const short8*)(ldsA + slot * 16384 + (mi * 16 + lr) * 128 +
                            ((kk * 64 + lk * 16) ^ xr));
  };
  auto rdB = [&](int t, int ni, int kk) -> short8 {
    const int slot = (2 * t + (wc >> 1)) & 3;
    return *(const short8*)(ldsB + slot * 16384 + ((wc & 1) * 64 + ni * 16 + lr) * 128 +
                            ((kk * 64 + lk * 16) ^ xr));
  };

  float4v acc[8][4] = {};

  // prologue: 7 halves in stream order; vmcnt(6) -> K0's 8 loads landed
  stageA(0, 0); stageA(0, 1); stageB(0, 0); stageB(0, 1);
  stageA(1, 0); stageA(1, 1); stageB(1, 0);
  asm volatile("s_waitcnt vmcnt(6)" ::: "memory");
  BARR();

#pragma unroll
  for (int t = 0; t < 8; ++t) {
    short8 a0[4][2], a1[4][2], b0[2][2], b1[2][2];
    // ---- ph1: read a[0-3], b[0-1]; stage K(t+1)B1; MFMA q0 ----
#pragma unroll
    for (int mi = 0; mi < 4; ++mi)
#pragma unroll
      for (int kk = 0; kk < 2; ++kk) a0[mi][kk] = rdA(t, mi, kk);
#pragma unroll
    for (int ni = 0; ni < 2; ++ni)
#pragma unroll
      for (int kk = 0; kk < 2; ++kk) b0[ni][kk] = rdB(t, ni, kk);
    if (t + 1 < 8) stageB(t + 1, 1);
    BARR();
    LGKM0();
    __builtin_amdgcn_s_setprio(1);
#pragma unroll
    for (int kk = 0; kk < 2; ++kk)
#pragma unroll
      for (int mi = 0; mi < 4; ++mi)
#pragma unroll
        for (int ni = 0; ni < 2; ++ni)
          acc[mi][ni] = __builtin_amdgcn_mfma_f32_16x16x32_bf16(a0[mi][kk], b0[ni][kk], acc[mi][ni], 0, 0, 0);
    __builtin_amdgcn_s_setprio(0);
    __builtin_amdgcn_sched_barrier(0);
    BARR();
    // ---- ph2: read a[4-7], b[2-3]; MFMA q1 (a0 x b1) ----
#pragma unroll
    for (int mi = 0; mi < 4; ++mi)
#pragma unroll
      for (int kk = 0; kk < 2; ++kk) a1[mi][kk] = rdA(t, mi + 4, kk);
#pragma unroll
    for (int ni = 0; ni < 2; ++ni)
#pragma unroll
      for (int kk = 0; kk < 2; ++kk) b1[ni][kk] = rdB(t, ni + 2, kk);
    BARR();
    LGKM0();
    __builtin_amdgcn_s_setprio(1);
#pragma unroll
    for (int kk = 0; kk < 2; ++kk)
#pragma unroll
      for (int mi = 0; mi < 4; ++mi)
#pragma unroll
        for (int ni = 0; ni < 2; ++ni)
          acc[mi][ni + 2] = __builtin_amdgcn_mfma_f32_16x16x32_bf16(a0[mi][kk], b1[ni][kk], acc[mi][ni + 2], 0, 0, 0);
    __builtin_amdgcn_s_setprio(0);
    __builtin_amdgcn_sched_barrier(0);
    BARR();
    // ---- ph3: stage K(t+2)A0,A1 (slots' readers done at ph2 lgkm); MFMA q2 --
    if (t + 2 < 8) { stageA(t + 2, 0); stageA(t + 2, 1); }
    __builtin_amdgcn_sched_barrier(0);
    __builtin_amdgcn_s_setprio(1);
#pragma unroll
    for (int kk = 0; kk < 2; ++kk)
#pragma unroll
      for (int mi = 0; mi < 4; ++mi)
#pragma unroll
        for (int ni = 0; ni < 2; ++ni)
          acc[mi + 4][ni] = __builtin_amdgcn_mfma_f32_16x16x32_bf16(a1[mi][kk], b0[ni][kk], acc[mi + 4][ni], 0, 0, 0);
    __builtin_amdgcn_s_setprio(0);
    __builtin_amdgcn_sched_barrier(0);
    BARR();
    // ---- ph4: stage K(t+2)B0; MFMA q3; boundary vmcnt ----
    if (t + 2 < 8) stageB(t + 2, 0);
    __builtin_amdgcn_sched_barrier(0);
    __builtin_amdgcn_s_setprio(1);
#pragma unroll
    for (int kk = 0; kk < 2; ++kk)
#pragma unroll
      for (int mi = 0; mi < 4; ++mi)
#pragma unroll
        for (int ni = 0; ni < 2; ++ni)
          acc[mi + 4][ni + 2] = __builtin_amdgcn_mfma_f32_16x16x32_bf16(a1[mi][kk], b1[ni][kk], acc[mi + 4][ni + 2], 0, 0, 0);
    __builtin_amdgcn_s_setprio(0);
    __builtin_amdgcn_sched_barrier(0);
    if (t < 6) {
      asm volatile("s_waitcnt vmcnt(6)" ::: "memory");   // K(t+1) fully landed
    } else if (t == 6) {
      asm volatile("s_waitcnt vmcnt(0)" ::: "memory");   // K7 fully landed
    }
    BARR();
  }

  // epilogue: C/D layout col=lane&15, row=(lane>>4)*4+r (m89-verified)
#pragma unroll
  for (int mi = 0; mi < 8; ++mi)
#pragma unroll
    for (int ni = 0; ni < 4; ++ni) {
      const int col = col0 + wc * 64 + ni * 16 + lr;
#pragma unroll
      for (int r = 0; r < 4; ++r) {
        const int row = row0 + wr * 128 + mi * 16 + lk * 4 + r;
        C[(size_t)row * 1536 + col] = f2bf(acc[mi][ni][r]);
      }
    }
}

// ---------------- K2: fused reduce (alpha/gq, beta/gk) + att ----------------
// One block per (b,h), 512 threads (8 waves). gk stays in LDS.
// QKV row layout per token: [q(512) | k(512) | v(512)], head slice h*64.
__global__ __launch_bounds__(512) void reduce_att(const ushort_t* __restrict__ QKV,
                                                  const float* __restrict__ Wr,
                                                  const float* __restrict__ w_alpha,
                                                  const float* __restrict__ w_beta,
                                                  ushort_t* __restrict__ att) {
  const int bh = blockIdx.x, b = bh >> 3, h = bh & 7;
  const int tid = threadIdx.x, wid = tid >> 6, lane = tid & 63;
  const int rsub = lane >> 3, dch = lane & 7;
  __shared__ float red[8][64];
  __shared__ float gq_s[64];
  __shared__ float gk_s[64];
  __shared__ __align__(16) ushort_t Ml[64 * 72];
  float wa[8], wb[8];
#pragma unroll
  for (int j = 0; j < 8; ++j) {
    wa[j] = w_alpha[dch * 8 + j] * SCALE_F;
    wb[j] = w_beta[dch * 8 + j] * SCALE_F;
  }
  const size_t base = (size_t)b * 1024;
  // ---- pass 1: alpha = softmax_D(q*wa), gq = sum_l alpha*q ----
  float acc[8] = {0, 0, 0, 0, 0, 0, 0, 0};
  for (int it = 0; it < 16; ++it) {
    const size_t t = base + it * 64 + wid * 8 + rsub;
    short8 raw = *(const short8*)(QKV + t * 1536 + h * 64 + dch * 8);
    float q[8], s[8];
#pragma unroll
    for (int j = 0; j < 8; ++j) { q[j] = bf2f((ushort_t)raw[j]); s[j] = q[j] * wa[j]; }
    float m = s[0];
#pragma unroll
    for (int j = 1; j < 8; ++j) m = fmaxf(m, s[j]);
    m = fmaxf(m, __shfl_xor(m, 1)); m = fmaxf(m, __shfl_xor(m, 2)); m = fmaxf(m, __shfl_xor(m, 4));
    float e[8], sum = 0.f;
#pragma unroll
    for (int j = 0; j < 8; ++j) { e[j] = __expf(s[j] - m); sum += e[j]; }
    sum += __shfl_xor(sum, 1); sum += __shfl_xor(sum, 2); sum += __shfl_xor(sum, 4);
    const float inv = 1.0f / sum;
#pragma unroll
    for (int j = 0; j < 8; ++j) acc[j] += e[j] * inv * q[j];
  }
#pragma unroll
  for (int msk = 8; msk < 64; msk <<= 1)
#pragma unroll
    for (int j = 0; j < 8; ++j) acc[j] += __shfl_xor(acc[j], msk);
  if (lane < 8) {
#pragma unroll
    for (int j = 0; j < 8; ++j) red[wid][lane * 8 + j] = acc[j];
  }
  __syncthreads();
  if (tid < 64) {
    float s = 0.f;
#pragma unroll
    for (int w = 0; w < 8; ++w) s += red[w][tid];
    gq_s[tid] = s;
  }
  __syncthreads();
  float gq[8];
#pragma unroll
  for (int j = 0; j < 8; ++j) gq[j] = gq_s[dch * 8 + j];
  // ---- pass 2: p = gq*k, beta = softmax_D(p*wb), gk = sum_l beta*p ----
  float gkacc[8] = {0, 0, 0, 0, 0, 0, 0, 0};
  for (int it = 0; it < 16; ++it) {
    const size_t t = base + it * 64 + wid * 8 + rsub;
    short8 raw = *(const short8*)(QKV + t * 1536 + 512 + h * 64 + dch * 8);
    float p[8], s[8];
#pragma unroll
    for (int j = 0; j < 8; ++j) { p[j] = gq[j] * bf2f((ushort_t)raw[j]); s[j] = p[j] * wb[j]; }
    float m = s[0];
#pragma unroll
    for (int j = 1; j < 8; ++j) m = fmaxf(m, s[j]);
    m = fmaxf(m, __shfl_xor(m, 1)); m = fmaxf(m, __shfl_xor(m, 2)); m = fmaxf(m, __shfl_xor(m, 4));
    float e[8], sum = 0.f;
#pragma unroll
    for (int j = 0; j < 8; ++j) { e[j] = __expf(s[j] - m); sum += e[j]; }
    sum += __shfl_xor(sum, 1); sum += __shfl_xor(sum, 2); sum += __shfl_xor(sum, 4);
    const float inv = 1.0f / sum;
#pragma unroll
    for (int j = 0; j < 8; ++j) gkacc[j] += e[j] * inv * p[j];
  }
#pragma unroll
  for (int msk = 8; msk < 64; msk <<= 1)
#pragma unroll
    for (int j = 0; j < 8; ++j) gkacc[j] += __shfl_xor(gkacc[j], msk);
  if (lane < 8) {
#pragma unroll
    for (int j = 0; j < 8; ++j) red[wid][lane * 8 + j] = gkacc[j];
  }
  __syncthreads();
  if (tid < 64) {
    float s = 0.f;
#pragma unroll
    for (int w = 0; w < 8; ++w) s += red[w][tid];
    gk_s[tid] = s;
  }
  __syncthreads();
  // ---- M = Wr * gk (row e scaled per-col d), bf16 in LDS (pad 72) ----
  for (int i = tid; i < 4096; i += 512) {
    const int e = i >> 6, d = i & 63;
    Ml[e * 72 + d] = f2bf(Wr[i] * gk_s[d]);
  }
  __syncthreads();
  // ---- att = relu(V @ M^T + Q): 8 waves x 128 tokens each ----
  const int lr = lane & 15, lk = lane >> 4;
  short8 bfr[4][2];
#pragma unroll
  for (int ni = 0; ni < 4; ++ni)
#pragma unroll
    for (int ks = 0; ks < 2; ++ks)
      bfr[ni][ks] = *(const short8*)&Ml[(ni * 16 + lr) * 72 + ks * 32 + lk * 8];
  const size_t tw = base + wid * 128;
  for (int c = 0; c < 2; ++c) {
    float4v oacc[4][4] = {};
#pragma unroll
    for (int ks = 0; ks < 2; ++ks) {
      short8 a[4];
#pragma unroll
      for (int mi = 0; mi < 4; ++mi) {
        const size_t t = tw + c * 64 + mi * 16 + lr;
        a[mi] = *(const short8*)(QKV + t * 1536 + 1024 + h * 64 + ks * 32 + lk * 8);
      }
#pragma unroll
      for (int mi = 0; mi < 4; ++mi)
#pragma unroll
        for (int ni = 0; ni < 4; ++ni)
          oacc[mi][ni] = __builtin_amdgcn_mfma_f32_16x16x32_bf16(a[mi], bfr[ni][ks], oacc[mi][ni], 0, 0, 0);
    }
#pragma unroll
    for (int mi = 0; mi < 4; ++mi)
#pragma unroll
      for (int ni = 0; ni < 4; ++ni)
#pragma unroll
        for (int r = 0; r < 4; ++r) {
          const size_t t = tw + c * 64 + mi * 16 + lk * 4 + r;
          const int e = ni * 16 + lr;
          float v = oacc[mi][ni][r] + bf2f(QKV[t * 1536 + h * 64 + e]);
          v = fmaxf(v, 0.0f);
          att[t * 512 + h * 64 + e] = f2bf(v);
        }
  }
}

// ---------------- K3: out = LN(att @ Wo^T + bo)*g + b  (fused epilogue) -----
// Grid 512 (M-tiles of 128 rows); 512 threads = 8 waves (2 wr x 4 wc),
// wave tile 64x128, BN=512 (full LN row in-block), BK=32 double-buffered.
__global__ __launch_bounds__(512, 2) void gemm_ln(const ushort_t* __restrict__ A,
                                                  const ushort_t* __restrict__ Bm,
                                                  float* __restrict__ out,
                                                  const float* __restrict__ bo,
                                                  const float* __restrict__ lng,
                                                  const float* __restrict__ lnb) {
  __shared__ __align__(16) ushort_t As[2][128 * 32];   // 2 x 8 KB
  __shared__ __align__(16) ushort_t Bs[2][512 * 32];   // 2 x 32 KB
  __shared__ float red_s[4][128][2];                   // per-wc row partials
  __shared__ float tot_s[128][2];
  const int tid = threadIdx.x, wid = tid >> 6, lane = tid & 63;
  const int wr = wid >> 2, wc = wid & 3;
  const int lr = lane & 15, lk = lane >> 4;
  const int row0 = blockIdx.x * 128;
  float4v acc[4][8] = {};

  const int la = lane * 16;
  const int ar = wid * 16 + (lane >> 2);     // A: wave wid stages rows wid*16..+15
  const int acb = (lane & 3) * 16;           // byte within 64B row

  auto stage = [&](int buf, int s) {
    const int k0b = s * 64;                  // byte offset into 1024B row
    gload16((const char*)A + (size_t)(row0 + ar) * 1024 + k0b + acb,
            (char*)&As[buf][0] + wid * 1024);
#pragma unroll
    for (int i = 0; i < 4; ++i) {
      const int dst = (wid * 4 + i) * 1024;  // B: 32 chunks of 16 rows
      const int br = (dst + la) >> 6;
      const int bcb = la & 63;
      gload16((const char*)Bm + (size_t)br * 1024 + k0b + bcb,
              (char*)&Bs[buf][0] + dst);
    }
  };

  stage(0, 0);
  __syncthreads();                           // implicit vmcnt(0) drain
  for (int s = 0; s < 16; ++s) {
    const int buf = s & 1;
    if (s < 15) stage(buf ^ 1, s + 1);       // prefetch overlaps compute
    short8 af[4], bf[8];
#pragma unroll
    for (int mi = 0; mi < 4; ++mi)
      af[mi] = *(const short8*)((const char*)&As[buf][0] + (wr * 64 + mi * 16 + lr) * 64 + lk * 16);
#pragma unroll
    for (int ni = 0; ni < 8; ++ni)
      bf[ni] = *(const short8*)((const char*)&Bs[buf][0] + (wc * 128 + ni * 16 + lr) * 64 + lk * 16);
#pragma unroll
    for (int mi = 0; mi < 4; ++mi)
#pragma unroll
      for (int ni = 0; ni < 8; ++ni)
        acc[mi][ni] = __builtin_amdgcn_mfma_f32_16x16x32_bf16(af[mi], bf[ni], acc[mi][ni], 0, 0, 0);
    __syncthreads();                         // drains vmcnt; protects dbuf swap
  }

  // ---- epilogue: bias + LayerNorm over the in-register full row ----
  float bov[8], gv[8], bv[8];
#pragma unroll
  for (int ni = 0; ni < 8; ++ni) {
    const int c = wc * 128 + ni * 16 + lr;
    bov[ni] = bo[c]; gv[ni] = lng[c]; bv[ni] = lnb[c];
  }
#pragma unroll
  for (int mi = 0; mi < 4; ++mi)
#pragma unroll
    for (int ni = 0; ni < 8; ++ni)
#pragma unroll
      for (int r = 0; r < 4; ++r)
        acc[mi][ni][r] += bov[ni];
#pragma unroll
  for (int mi = 0; mi < 4; ++mi)
#pragma unroll
    for (int r = 0; r < 4; ++r) {
      float s = 0.f, q = 0.f;
#pragma unroll
      for (int ni = 0; ni < 8; ++ni) { const float v = acc[mi][ni][r]; s += v; q += v * v; }
      s += __shfl_xor(s, 1); q += __shfl_xor(q, 1);
      s += __shfl_xor(s, 2); q += __shfl_xor(q, 2);
      s += __shfl_xor(s, 4); q += __shfl_xor(q, 4);
      s += __shfl_xor(s, 8); q += __shfl_xor(q, 8);
      if (lr == 0) {
        const int rb = wr * 64 + mi * 16 + lk * 4 + r;
        red_s[wc][rb][0] = s;
        red_s[wc][rb][1] = q;
      }
    }
  __syncthreads();
  if (tid < 128) {
    tot_s[tid][0] = red_s[0][tid][0] + red_s[1][tid][0] + red_s[2][tid][0] + red_s[3][tid][0];
    tot_s[tid][1] = red_s[0][tid][1] + red_s[1][tid][1] + red_s[2][tid][1] + red_s[3][tid][1];
  }
  __syncthreads();
#pragma unroll
  for (int mi = 0; mi < 4; ++mi)
#pragma unroll
    for (int r = 0; r < 4; ++r) {
      const int rb = wr * 64 + mi * 16 + lk * 4 + r;
      const float mu = tot_s[rb][0] * (1.f / 512.f);
      const float var = tot_s[rb][1] * (1.f / 512.f) - mu * mu;
      const float rs = rsqrtf(var + EPSF);
      float* op = out + (size_t)(row0 + rb) * 512 + wc * 128 + lr;
#pragma unroll
      for (int ni = 0; ni < 8; ++ni)
        op[ni * 16] = (acc[mi][ni][r] - mu) * rs * gv[ni] + bv[ni];
    }
}

extern "C" void kernel_launch(void* const* d_in, const int* in_sizes, int n_in,
                              void* d_out, int out_size, void* d_ws, size_t ws_size,
                              hipStream_t stream) {
  const float* X       = (const float*)d_in[0];
  // d_in[1] = batch_scopes (int64) — contiguous equal scopes, unused
  const float* Wq      = (const float*)d_in[2];
  const float* Wk      = (const float*)d_in[3];
  const float* Wv      = (const float*)d_in[4];
  const float* Wr      = (const float*)d_in[5];
  const float* w_alpha = (const float*)d_in[6];
  const float* w_beta  = (const float*)d_in[7];
  const float* Wo      = (const float*)d_in[8];
  const float* bo      = (const float*)d_in[9];
  const float* ln_g    = (const float*)d_in[10];
  const float* ln_b    = (const float*)d_in[11];

  char* ws = (char*)d_ws;
  ushort_t* Xb   = (ushort_t*)(ws);                 // 67,108,864 B
  ushort_t* Wqkv = (ushort_t*)(ws + 67108864);      //  1,572,864 B
  ushort_t* Wob  = (ushort_t*)(ws + 68681728);      //    524,288 B
  ushort_t* QKV  = (ushort_t*)(ws + 69206016);      // 201,326,592 B
  ushort_t* att  = Xb;                              // alias: Xb dead after K1
  float* out = (float*)d_out;

  hipLaunchKernelGGL(cvt_x, dim3(16384), dim3(256), 0, stream, X, Xb);
  hipLaunchKernelGGL(cvt_w, dim3(4096), dim3(256), 0, stream, Wq, Wk, Wv, Wo, Wqkv, Wob);
  hipLaunchKernelGGL(gemm8p, dim3(1536), dim3(512), 0, stream, Xb, Wqkv, QKV);
  hipLaunchKernelGGL(reduce_att, dim3(512), dim3(512), 0, stream,
                     QKV, Wr, w_alpha, w_beta, att);
  hipLaunchKernelGGL(gemm_ln, dim3(512), dim3(512), 0, stream,
                     att, Wob, out, bo, ln_g, ln_b);
}

// Round 4
// 328.809 us; speedup vs baseline: 1.2910x; 1.1287x over previous
//
#include <hip/hip_runtime.h>
#include <stdint.h>

// BondFastAttention on MI355X (gfx950)
// B=64 graphs x L=1024 bonds, HID=512, HEADS=8, D=64. Contiguous equal scopes
// -> pad_sequence == reshape, so batch_scopes is ignored.
//
// Pipeline (round 4):
//   K0  cvt_x:   X f32 -> bf16 (Xb)
//   K0b cvt_w:   Wq|Wk|Wv -> Wqkv bf16 (1536x512), Wo -> bf16
//   K1  gemm8p:  QKV = Xb @ Wqkv^T  -- 256^2 tile, 4-phase counted-vmcnt
//   R1  reduce_gq: gq partials per (b,h,Lchunk)   [no atomics -> determ.]
//   R2  reduce_gk: gk partials (folds gq partials in prologue)
//   R3  att_k:   att = relu([V|Q] @ [M|I]^T), M = Wr*gk  (identity-MFMA Q-add)
//   K3  gemm_ln: out = LN(att @ Wo^T + bo)*g + b  (fused epilogue)
//
// ws: Xb 0..67108864 | Wqkv ..68681728 | Wob ..69206016 | QKV ..270532608 |
//     gq_part ..271056896 | gk_part ..271581184
// att aliases Xb (Xb dead after K1).

#define SCALE_F 0.125f   // D^-0.5
#define EPSF 1e-5f

typedef __attribute__((ext_vector_type(8))) short short8;
typedef __attribute__((ext_vector_type(4))) float float4v;
typedef unsigned short ushort_t;

__device__ __forceinline__ ushort_t f2bf(float f) {
  uint32_t u = __builtin_bit_cast(uint32_t, f);
  u += 0x7fffu + ((u >> 16) & 1u);          // round-to-nearest-even
  return (ushort_t)(u >> 16);
}
__device__ __forceinline__ float bf2f(ushort_t s) {
  uint32_t u = ((uint32_t)s) << 16;
  return __builtin_bit_cast(float, u);
}

// async global->LDS, 16B per lane; LDS dest = wave-uniform base + lane*16
__device__ __forceinline__ void gload16(const void* g, void* l) {
  __builtin_amdgcn_global_load_lds(
      (__attribute__((address_space(1))) char*)(char*)const_cast<void*>(g),
      (__attribute__((address_space(3))) char*)(char*)l, 16, 0, 0);
}

#define BARR() asm volatile("s_barrier" ::: "memory")
#define LGKM0() do { asm volatile("s_waitcnt lgkmcnt(0)" ::: "memory"); \
                     __builtin_amdgcn_sched_barrier(0); } while (0)

// ---------------- K0: X f32 -> bf16 (8 elems/thread) ----------------
__global__ __launch_bounds__(256) void cvt_x(const float* __restrict__ X,
                                             ushort_t* __restrict__ Xb) {
  const int i = blockIdx.x * 256 + threadIdx.x;
  const float4v* src = (const float4v*)X;
  float4v v0 = src[(size_t)i * 2];
  float4v v1 = src[(size_t)i * 2 + 1];
  short8 o;
#pragma unroll
  for (int j = 0; j < 4; ++j) {
    o[j]     = (short)f2bf(v0[j]);
    o[j + 4] = (short)f2bf(v1[j]);
  }
  ((short8*)Xb)[i] = o;
}

// ---------------- K0b: weights -> bf16 ----------------
__global__ __launch_bounds__(256) void cvt_w(const float* __restrict__ Wq,
                                             const float* __restrict__ Wk,
                                             const float* __restrict__ Wv,
                                             const float* __restrict__ Wo,
                                             ushort_t* __restrict__ Wqkv,
                                             ushort_t* __restrict__ Wob) {
  const int i = blockIdx.x * 256 + threadIdx.x;   // 1,048,576 total
  if (i < 262144)        Wqkv[i] = f2bf(Wq[i]);
  else if (i < 524288)   Wqkv[i] = f2bf(Wk[i - 262144]);
  else if (i < 786432)   Wqkv[i] = f2bf(Wv[i - 524288]);
  else                   Wob[i - 786432] = f2bf(Wo[i - 786432]);
}

// ---------------- K1: QKV = Xb @ Wqkv^T, 256x256 tile, 8-phase schedule -----
// (unchanged from round 3; see that round's ledger derivation)
__global__ __launch_bounds__(512, 2) void gemm8p(const ushort_t* __restrict__ A,
                                                 const ushort_t* __restrict__ Bm,
                                                 ushort_t* __restrict__ C) {
  __shared__ __align__(16) char ldsA[65536];
  __shared__ __align__(16) char ldsB[65536];
  const int swz = (blockIdx.x & 7) * 192 + (blockIdx.x >> 3);
  const int tm = swz / 6, tn = swz % 6;
  const int row0 = tm * 256, col0 = tn * 256;
  const int tid = threadIdx.x, wid = tid >> 6, lane = tid & 63;
  const int wr = wid >> 2, wc = wid & 3;
  const int lr = lane & 15, lk = lane >> 4;
  const int xr = (lr & 7) << 4;               // read-side XOR (bytes)

  auto stageA = [&](int kt, int h) {
    const int slot = (2 * kt + h) & 3;
    const int rowbase = row0 + h * 128;
#pragma unroll
    for (int i = 0; i < 2; ++i) {
      const int o = i * 8192 + wid * 1024 + lane * 16;
      const int r = o >> 7, x = o & 127;
      gload16((const char*)A + (size_t)(rowbase + r) * 1024 + kt * 128 + (x ^ ((r & 7) << 4)),
              ldsA + slot * 16384 + i * 8192 + wid * 1024);
    }
  };
  auto stageB = [&](int kt, int h) {
    const int slot = (2 * kt + h) & 3;
    const int rowbase = col0 + h * 128;
#pragma unroll
    for (int i = 0; i < 2; ++i) {
      const int o = i * 8192 + wid * 1024 + lane * 16;
      const int r = o >> 7, x = o & 127;
      gload16((const char*)Bm + (size_t)(rowbase + r) * 1024 + kt * 128 + (x ^ ((r & 7) << 4)),
              ldsB + slot * 16384 + i * 8192 + wid * 1024);
    }
  };
  auto rdA = [&](int t, int mi, int kk) -> short8 {
    const int slot = (2 * t + wr) & 3;
    return *(const short8*)(ldsA + slot * 16384 + (mi * 16 + lr) * 128 +
                            ((kk * 64 + lk * 16) ^ xr));
  };
  auto rdB = [&](int t, int ni, int kk) -> short8 {
    const int slot = (2 * t + (wc >> 1)) & 3;
    return *(const short8*)(ldsB + slot * 16384 + ((wc & 1) * 64 + ni * 16 + lr) * 128 +
                            ((kk * 64 + lk * 16) ^ xr));
  };

  float4v acc[8][4] = {};

  stageA(0, 0); stageA(0, 1); stageB(0, 0); stageB(0, 1);
  stageA(1, 0); stageA(1, 1); stageB(1, 0);
  asm volatile("s_waitcnt vmcnt(6)" ::: "memory");
  BARR();

#pragma unroll
  for (int t = 0; t < 8; ++t) {
    short8 a0[4][2], a1[4][2], b0[2][2], b1[2][2];
#pragma unroll
    for (int mi = 0; mi < 4; ++mi)
#pragma unroll
      for (int kk = 0; kk < 2; ++kk) a0[mi][kk] = rdA(t, mi, kk);
#pragma unroll
    for (int ni = 0; ni < 2; ++ni)
#pragma unroll
      for (int kk = 0; kk < 2; ++kk) b0[ni][kk] = rdB(t, ni, kk);
    if (t + 1 < 8) stageB(t + 1, 1);
    BARR();
    LGKM0();
    __builtin_amdgcn_s_setprio(1);
#pragma unroll
    for (int kk = 0; kk < 2; ++kk)
#pragma unroll
      for (int mi = 0; mi < 4; ++mi)
#pragma unroll
        for (int ni = 0; ni < 2; ++ni)
          acc[mi][ni] = __builtin_amdgcn_mfma_f32_16x16x32_bf16(a0[mi][kk], b0[ni][kk], acc[mi][ni], 0, 0, 0);
    __builtin_amdgcn_s_setprio(0);
    __builtin_amdgcn_sched_barrier(0);
    BARR();
#pragma unroll
    for (int mi = 0; mi < 4; ++mi)
#pragma unroll
      for (int kk = 0; kk < 2; ++kk) a1[mi][kk] = rdA(t, mi + 4, kk);
#pragma unroll
    for (int ni = 0; ni < 2; ++ni)
#pragma unroll
      for (int kk = 0; kk < 2; ++kk) b1[ni][kk] = rdB(t, ni + 2, kk);
    BARR();
    LGKM0();
    __builtin_amdgcn_s_setprio(1);
#pragma unroll
    for (int kk = 0; kk < 2; ++kk)
#pragma unroll
      for (int mi = 0; mi < 4; ++mi)
#pragma unroll
        for (int ni = 0; ni < 2; ++ni)
          acc[mi][ni + 2] = __builtin_amdgcn_mfma_f32_16x16x32_bf16(a0[mi][kk], b1[ni][kk], acc[mi][ni + 2], 0, 0, 0);
    __builtin_amdgcn_s_setprio(0);
    __builtin_amdgcn_sched_barrier(0);
    BARR();
    if (t + 2 < 8) { stageA(t + 2, 0); stageA(t + 2, 1); }
    __builtin_amdgcn_sched_barrier(0);
    __builtin_amdgcn_s_setprio(1);
#pragma unroll
    for (int kk = 0; kk < 2; ++kk)
#pragma unroll
      for (int mi = 0; mi < 4; ++mi)
#pragma unroll
        for (int ni = 0; ni < 2; ++ni)
          acc[mi + 4][ni] = __builtin_amdgcn_mfma_f32_16x16x32_bf16(a1[mi][kk], b0[ni][kk], acc[mi + 4][ni], 0, 0, 0);
    __builtin_amdgcn_s_setprio(0);
    __builtin_amdgcn_sched_barrier(0);
    BARR();
    if (t + 2 < 8) stageB(t + 2, 0);
    __builtin_amdgcn_sched_barrier(0);
    __builtin_amdgcn_s_setprio(1);
#pragma unroll
    for (int kk = 0; kk < 2; ++kk)
#pragma unroll
      for (int mi = 0; mi < 4; ++mi)
#pragma unroll
        for (int ni = 0; ni < 2; ++ni)
          acc[mi + 4][ni + 2] = __builtin_amdgcn_mfma_f32_16x16x32_bf16(a1[mi][kk], b1[ni][kk], acc[mi + 4][ni + 2], 0, 0, 0);
    __builtin_amdgcn_s_setprio(0);
    __builtin_amdgcn_sched_barrier(0);
    if (t < 6) {
      asm volatile("s_waitcnt vmcnt(6)" ::: "memory");
    } else if (t == 6) {
      asm volatile("s_waitcnt vmcnt(0)" ::: "memory");
    }
    BARR();
  }

#pragma unroll
  for (int mi = 0; mi < 8; ++mi)
#pragma unroll
    for (int ni = 0; ni < 4; ++ni) {
      const int col = col0 + wc * 64 + ni * 16 + lr;
#pragma unroll
      for (int r = 0; r < 4; ++r) {
        const int row = row0 + wr * 128 + mi * 16 + lk * 4 + r;
        C[(size_t)row * 1536 + col] = f2bf(acc[mi][ni][r]);
      }
    }
}

// ---------------- R1: gq partials ----------------
// Grid 2048 = (bh=512) x (ch=4); 256 thr. Each block: 256 tokens.
// Lane map: rsub=lane>>3 (token), dch=lane&7 (8 bf16 of D). Softmax over D=64
// via intra-lane max/sum + shfl_xor {1,2,4}. Partial gq -> gq_part[bx][64].
__global__ __launch_bounds__(256) void reduce_gq(const ushort_t* __restrict__ QKV,
                                                 const float* __restrict__ w_alpha,
                                                 float* __restrict__ gq_part) {
  const int bx = blockIdx.x, bh = bx >> 2, ch = bx & 3;
  const int b = bh >> 3, h = bh & 7;
  const int tid = threadIdx.x, wid = tid >> 6, lane = tid & 63;
  const int rsub = lane >> 3, dch = lane & 7;
  __shared__ float red[4][64];
  float wa[8];
#pragma unroll
  for (int j = 0; j < 8; ++j) wa[j] = w_alpha[dch * 8 + j] * SCALE_F;
  const size_t base = (size_t)b * 1024 + ch * 256;
  float acc[8] = {0, 0, 0, 0, 0, 0, 0, 0};
  for (int it = 0; it < 8; ++it) {
    const size_t t = base + it * 32 + wid * 8 + rsub;
    short8 raw = *(const short8*)(QKV + t * 1536 + h * 64 + dch * 8);
    float q[8], s[8];
#pragma unroll
    for (int j = 0; j < 8; ++j) { q[j] = bf2f((ushort_t)raw[j]); s[j] = q[j] * wa[j]; }
    float m = s[0];
#pragma unroll
    for (int j = 1; j < 8; ++j) m = fmaxf(m, s[j]);
    m = fmaxf(m, __shfl_xor(m, 1)); m = fmaxf(m, __shfl_xor(m, 2)); m = fmaxf(m, __shfl_xor(m, 4));
    float e[8], sum = 0.f;
#pragma unroll
    for (int j = 0; j < 8; ++j) { e[j] = __expf(s[j] - m); sum += e[j]; }
    sum += __shfl_xor(sum, 1); sum += __shfl_xor(sum, 2); sum += __shfl_xor(sum, 4);
    const float inv = 1.0f / sum;
#pragma unroll
    for (int j = 0; j < 8; ++j) acc[j] += e[j] * inv * q[j];
  }
#pragma unroll
  for (int msk = 8; msk < 64; msk <<= 1)
#pragma unroll
    for (int j = 0; j < 8; ++j) acc[j] += __shfl_xor(acc[j], msk);
  if (lane < 8) {
#pragma unroll
    for (int j = 0; j < 8; ++j) red[wid][lane * 8 + j] = acc[j];
  }
  __syncthreads();
  if (tid < 64)
    gq_part[(size_t)bx * 64 + tid] = red[0][tid] + red[1][tid] + red[2][tid] + red[3][tid];
}

// ---------------- R2: gk partials (folds gq partials in prologue) ----------
__global__ __launch_bounds__(256) void reduce_gk(const ushort_t* __restrict__ QKV,
                                                 const float* __restrict__ w_beta,
                                                 const float* __restrict__ gq_part,
                                                 float* __restrict__ gk_part) {
  const int bx = blockIdx.x, bh = bx >> 2, ch = bx & 3;
  const int b = bh >> 3, h = bh & 7;
  const int tid = threadIdx.x, wid = tid >> 6, lane = tid & 63;
  const int rsub = lane >> 3, dch = lane & 7;
  __shared__ float red[4][64];
  __shared__ float gq_s[64];
  if (tid < 64) {
    float s = 0.f;
#pragma unroll
    for (int c = 0; c < 4; ++c) s += gq_part[(size_t)(bh * 4 + c) * 64 + tid];
    gq_s[tid] = s;
  }
  __syncthreads();
  float wb[8], gq[8];
#pragma unroll
  for (int j = 0; j < 8; ++j) {
    wb[j] = w_beta[dch * 8 + j] * SCALE_F;
    gq[j] = gq_s[dch * 8 + j];
  }
  const size_t base = (size_t)b * 1024 + ch * 256;
  float acc[8] = {0, 0, 0, 0, 0, 0, 0, 0};
  for (int it = 0; it < 8; ++it) {
    const size_t t = base + it * 32 + wid * 8 + rsub;
    short8 raw = *(const short8*)(QKV + t * 1536 + 512 + h * 64 + dch * 8);
    float p[8], s[8];
#pragma unroll
    for (int j = 0; j < 8; ++j) { p[j] = gq[j] * bf2f((ushort_t)raw[j]); s[j] = p[j] * wb[j]; }
    float m = s[0];
#pragma unroll
    for (int j = 1; j < 8; ++j) m = fmaxf(m, s[j]);
    m = fmaxf(m, __shfl_xor(m, 1)); m = fmaxf(m, __shfl_xor(m, 2)); m = fmaxf(m, __shfl_xor(m, 4));
    float e[8], sum = 0.f;
#pragma unroll
    for (int j = 0; j < 8; ++j) { e[j] = __expf(s[j] - m); sum += e[j]; }
    sum += __shfl_xor(sum, 1); sum += __shfl_xor(sum, 2); sum += __shfl_xor(sum, 4);
    const float inv = 1.0f / sum;
#pragma unroll
    for (int j = 0; j < 8; ++j) acc[j] += e[j] * inv * p[j];
  }
#pragma unroll
  for (int msk = 8; msk < 64; msk <<= 1)
#pragma unroll
    for (int j = 0; j < 8; ++j) acc[j] += __shfl_xor(acc[j], msk);
  if (lane < 8) {
#pragma unroll
    for (int j = 0; j < 8; ++j) red[wid][lane * 8 + j] = acc[j];
  }
  __syncthreads();
  if (tid < 64)
    gk_part[(size_t)bx * 64 + tid] = red[0][tid] + red[1][tid] + red[2][tid] + red[3][tid];
}

// ---------------- R3: att = relu([V|Q] @ [M|I]^T), M = Wr*gk ----------------
// Grid 2048 = (bh=512) x (tc=4); 256 thr = 4 waves x 64 tokens. Q-residual is
// added via MFMA against an in-register bf16 identity fragment (exact: 1.0*q),
// so ALL global reads are coalesced short8. Stores scalar bf16 (L2 merges).
__global__ __launch_bounds__(256) void att_k(const ushort_t* __restrict__ QKV,
                                             const float* __restrict__ Wr,
                                             const float* __restrict__ gk_part,
                                             ushort_t* __restrict__ att) {
  const int bx = blockIdx.x, bh = bx >> 2, tc = bx & 3;
  const int b = bh >> 3, h = bh & 7;
  const int tid = threadIdx.x, wid = tid >> 6, lane = tid & 63;
  __shared__ float gk_s[64];
  __shared__ __align__(16) ushort_t Ml[64 * 72];
  if (tid < 64) {
    float s = 0.f;
#pragma unroll
    for (int c = 0; c < 4; ++c) s += gk_part[(size_t)(bh * 4 + c) * 64 + tid];
    gk_s[tid] = s;
  }
  __syncthreads();
  for (int i = tid; i < 4096; i += 256) {
    const int e = i >> 6, d = i & 63;
    Ml[e * 72 + d] = f2bf(Wr[i] * gk_s[d]);
  }
  __syncthreads();
  const int lr = lane & 15, lk = lane >> 4;
  short8 bfr[4][2], bfi[4][2];
#pragma unroll
  for (int ni = 0; ni < 4; ++ni)
#pragma unroll
    for (int ks = 0; ks < 2; ++ks) {
      bfr[ni][ks] = *(const short8*)&Ml[(ni * 16 + lr) * 72 + ks * 32 + lk * 8];
#pragma unroll
      for (int j = 0; j < 8; ++j)
        bfi[ni][ks][j] = (ni * 16 + lr == ks * 32 + lk * 8 + j) ? (short)0x3F80 : (short)0;
    }
  const size_t tw = (size_t)b * 1024 + tc * 256 + wid * 64;
  float4v oacc[4][4] = {};
#pragma unroll
  for (int ks = 0; ks < 2; ++ks) {
    short8 a[4], aq[4];
#pragma unroll
    for (int mi = 0; mi < 4; ++mi) {
      const size_t t = tw + mi * 16 + lr;
      a[mi]  = *(const short8*)(QKV + t * 1536 + 1024 + h * 64 + ks * 32 + lk * 8);  // V
      aq[mi] = *(const short8*)(QKV + t * 1536 +        h * 64 + ks * 32 + lk * 8);  // Q
    }
#pragma unroll
    for (int mi = 0; mi < 4; ++mi)
#pragma unroll
      for (int ni = 0; ni < 4; ++ni) {
        oacc[mi][ni] = __builtin_amdgcn_mfma_f32_16x16x32_bf16(a[mi],  bfr[ni][ks], oacc[mi][ni], 0, 0, 0);
        oacc[mi][ni] = __builtin_amdgcn_mfma_f32_16x16x32_bf16(aq[mi], bfi[ni][ks], oacc[mi][ni], 0, 0, 0);
      }
  }
#pragma unroll
  for (int mi = 0; mi < 4; ++mi)
#pragma unroll
    for (int ni = 0; ni < 4; ++ni)
#pragma unroll
      for (int r = 0; r < 4; ++r) {
        const size_t t = tw + mi * 16 + lk * 4 + r;
        const int e = ni * 16 + lr;
        att[t * 512 + h * 64 + e] = f2bf(fmaxf(oacc[mi][ni][r], 0.0f));
      }
}

// ---------------- K3: out = LN(att @ Wo^T + bo)*g + b  (fused epilogue) -----
__global__ __launch_bounds__(512, 2) void gemm_ln(const ushort_t* __restrict__ A,
                                                  const ushort_t* __restrict__ Bm,
                                                  float* __restrict__ out,
                                                  const float* __restrict__ bo,
                                                  const float* __restrict__ lng,
                                                  const float* __restrict__ lnb) {
  __shared__ __align__(16) ushort_t As[2][128 * 32];   // 2 x 8 KB
  __shared__ __align__(16) ushort_t Bs[2][512 * 32];   // 2 x 32 KB
  __shared__ float red_s[4][128][2];
  __shared__ float tot_s[128][2];
  const int tid = threadIdx.x, wid = tid >> 6, lane = tid & 63;
  const int wr = wid >> 2, wc = wid & 3;
  const int lr = lane & 15, lk = lane >> 4;
  const int row0 = blockIdx.x * 128;
  float4v acc[4][8] = {};

  const int la = lane * 16;
  const int ar = wid * 16 + (lane >> 2);
  const int acb = (lane & 3) * 16;

  auto stage = [&](int buf, int s) {
    const int k0b = s * 64;
    gload16((const char*)A + (size_t)(row0 + ar) * 1024 + k0b + acb,
            (char*)&As[buf][0] + wid * 1024);
#pragma unroll
    for (int i = 0; i < 4; ++i) {
      const int dst = (wid * 4 + i) * 1024;
      const int br = (dst + la) >> 6;
      const int bcb = la & 63;
      gload16((const char*)Bm + (size_t)br * 1024 + k0b + bcb,
              (char*)&Bs[buf][0] + dst);
    }
  };

  stage(0, 0);
  __syncthreads();
  for (int s = 0; s < 16; ++s) {
    const int buf = s & 1;
    if (s < 15) stage(buf ^ 1, s + 1);
    short8 af[4], bf[8];
#pragma unroll
    for (int mi = 0; mi < 4; ++mi)
      af[mi] = *(const short8*)((const char*)&As[buf][0] + (wr * 64 + mi * 16 + lr) * 64 + lk * 16);
#pragma unroll
    for (int ni = 0; ni < 8; ++ni)
      bf[ni] = *(const short8*)((const char*)&Bs[buf][0] + (wc * 128 + ni * 16 + lr) * 64 + lk * 16);
#pragma unroll
    for (int mi = 0; mi < 4; ++mi)
#pragma unroll
      for (int ni = 0; ni < 8; ++ni)
        acc[mi][ni] = __builtin_amdgcn_mfma_f32_16x16x32_bf16(af[mi], bf[ni], acc[mi][ni], 0, 0, 0);
    __syncthreads();
  }

  float bov[8], gv[8], bv[8];
#pragma unroll
  for (int ni = 0; ni < 8; ++ni) {
    const int c = wc * 128 + ni * 16 + lr;
    bov[ni] = bo[c]; gv[ni] = lng[c]; bv[ni] = lnb[c];
  }
#pragma unroll
  for (int mi = 0; mi < 4; ++mi)
#pragma unroll
    for (int ni = 0; ni < 8; ++ni)
#pragma unroll
      for (int r = 0; r < 4; ++r)
        acc[mi][ni][r] += bov[ni];
#pragma unroll
  for (int mi = 0; mi < 4; ++mi)
#pragma unroll
    for (int r = 0; r < 4; ++r) {
      float s = 0.f, q = 0.f;
#pragma unroll
      for (int ni = 0; ni < 8; ++ni) { const float v = acc[mi][ni][r]; s += v; q += v * v; }
      s += __shfl_xor(s, 1); q += __shfl_xor(q, 1);
      s += __shfl_xor(s, 2); q += __shfl_xor(q, 2);
      s += __shfl_xor(s, 4); q += __shfl_xor(q, 4);
      s += __shfl_xor(s, 8); q += __shfl_xor(q, 8);
      if (lr == 0) {
        const int rb = wr * 64 + mi * 16 + lk * 4 + r;
        red_s[wc][rb][0] = s;
        red_s[wc][rb][1] = q;
      }
    }
  __syncthreads();
  if (tid < 128) {
    tot_s[tid][0] = red_s[0][tid][0] + red_s[1][tid][0] + red_s[2][tid][0] + red_s[3][tid][0];
    tot_s[tid][1] = red_s[0][tid][1] + red_s[1][tid][1] + red_s[2][tid][1] + red_s[3][tid][1];
  }
  __syncthreads();
#pragma unroll
  for (int mi = 0; mi < 4; ++mi)
#pragma unroll
    for (int r = 0; r < 4; ++r) {
      const int rb = wr * 64 + mi * 16 + lk * 4 + r;
      const float mu = tot_s[rb][0] * (1.f / 512.f);
      const float var = tot_s[rb][1] * (1.f / 512.f) - mu * mu;
      const float rs = rsqrtf(var + EPSF);
      float* op = out + (size_t)(row0 + rb) * 512 + wc * 128 + lr;
#pragma unroll
      for (int ni = 0; ni < 8; ++ni)
        op[ni * 16] = (acc[mi][ni][r] - mu) * rs * gv[ni] + bv[ni];
    }
}

extern "C" void kernel_launch(void* const* d_in, const int* in_sizes, int n_in,
                              void* d_out, int out_size, void* d_ws, size_t ws_size,
                              hipStream_t stream) {
  const float* X       = (const float*)d_in[0];
  // d_in[1] = batch_scopes (int64) — contiguous equal scopes, unused
  const float* Wq      = (const float*)d_in[2];
  const float* Wk      = (const float*)d_in[3];
  const float* Wv      = (const float*)d_in[4];
  const float* Wr      = (const float*)d_in[5];
  const float* w_alpha = (const float*)d_in[6];
  const float* w_beta  = (const float*)d_in[7];
  const float* Wo      = (const float*)d_in[8];
  const float* bo      = (const float*)d_in[9];
  const float* ln_g    = (const float*)d_in[10];
  const float* ln_b    = (const float*)d_in[11];

  char* ws = (char*)d_ws;
  ushort_t* Xb      = (ushort_t*)(ws);              // 67,108,864 B
  ushort_t* Wqkv    = (ushort_t*)(ws + 67108864);   //  1,572,864 B
  ushort_t* Wob     = (ushort_t*)(ws + 68681728);   //    524,288 B
  ushort_t* QKV     = (ushort_t*)(ws + 69206016);   // 201,326,592 B
  float*    gq_part = (float*)(ws + 270532608);     //    524,288 B
  float*    gk_part = (float*)(ws + 271056896);     //    524,288 B
  ushort_t* att     = Xb;                           // alias: Xb dead after K1
  float* out = (float*)d_out;

  hipLaunchKernelGGL(cvt_x, dim3(16384), dim3(256), 0, stream, X, Xb);
  hipLaunchKernelGGL(cvt_w, dim3(4096), dim3(256), 0, stream, Wq, Wk, Wv, Wo, Wqkv, Wob);
  hipLaunchKernelGGL(gemm8p, dim3(1536), dim3(512), 0, stream, Xb, Wqkv, QKV);
  hipLaunchKernelGGL(reduce_gq, dim3(2048), dim3(256), 0, stream, QKV, w_alpha, gq_part);
  hipLaunchKernelGGL(reduce_gk, dim3(2048), dim3(256), 0, stream, QKV, w_beta, gq_part, gk_part);
  hipLaunchKernelGGL(att_k, dim3(2048), dim3(256), 0, stream, QKV, Wr, gk_part, att);
  hipLaunchKernelGGL(gemm_ln, dim3(512), dim3(512), 0, stream,
                     att, Wob, out, bo, ln_g, ln_b);
}